// Round 2
// baseline (2613.255 us; speedup 1.0000x reference)
//
#include <hip/hip_runtime.h>

#define BB 16
#define NN 4096
#define SS 1024
#define KNB 32

// ---- ws layout (in 4-byte words) ----
#define FPSIDX_OFF 0                         // int[BB*SS]
#define GIDX_OFF   (BB*SS)                   // int[BB*SS*KNB]
#define NORM_OFF   (GIDX_OFF + BB*SS*KNB)    // float[BB*NN]
#define FPIN_OFF   (NORM_OFF + BB*NN)        // float[BB*SS*9]
#define WF_OFF     (FPIN_OFF + BB*SS*9)      // float[13120]

// folded-weight layout (floats, within wf)
#define W0T 0          // [9][64]
#define B0F 576
#define W1T 640        // [64][64]
#define B1F 4736
#define W2T 4800       // [64][128]
#define B2F 12992

#define LDQ(p) (*(const float4*)(p))

__device__ __forceinline__ void fma8(float* h, float v, const float* wp){
  float4 w0 = LDQ(wp); float4 w1 = LDQ(wp+4);
  h[0]=fmaf(v,w0.x,h[0]); h[1]=fmaf(v,w0.y,h[1]); h[2]=fmaf(v,w0.z,h[2]); h[3]=fmaf(v,w0.w,h[3]);
  h[4]=fmaf(v,w1.x,h[4]); h[5]=fmaf(v,w1.y,h[5]); h[6]=fmaf(v,w1.z,h[6]); h[7]=fmaf(v,w1.w,h[7]);
}

__device__ __forceinline__ void fma16(float* a, float v, const float* wp){
  float4 w0 = LDQ(wp); float4 w1 = LDQ(wp+4); float4 w2 = LDQ(wp+8); float4 w3 = LDQ(wp+12);
  a[0] =fmaf(v,w0.x,a[0]);  a[1] =fmaf(v,w0.y,a[1]);  a[2] =fmaf(v,w0.z,a[2]);  a[3] =fmaf(v,w0.w,a[3]);
  a[4] =fmaf(v,w1.x,a[4]);  a[5] =fmaf(v,w1.y,a[5]);  a[6] =fmaf(v,w1.z,a[6]);  a[7] =fmaf(v,w1.w,a[7]);
  a[8] =fmaf(v,w2.x,a[8]);  a[9] =fmaf(v,w2.y,a[9]);  a[10]=fmaf(v,w2.z,a[10]); a[11]=fmaf(v,w2.w,a[11]);
  a[12]=fmaf(v,w3.x,a[12]); a[13]=fmaf(v,w3.y,a[13]); a[14]=fmaf(v,w3.z,a[14]); a[15]=fmaf(v,w3.w,a[15]);
}

__device__ __forceinline__ unsigned long long sx64(unsigned long long v, int m){
  unsigned lo = __shfl_xor((unsigned)v, m);
  unsigned hi = __shfl_xor((unsigned)(v>>32), m);
  return ((unsigned long long)hi<<32) | lo;
}

// ---- K1: fold BN into weights, transpose to [c][f] ----
__global__ __launch_bounds__(128) void k_fold(
    const float* W0,const float* b0,const float* g0,const float* be0,const float* m0,const float* v0,
    const float* W1,const float* b1,const float* g1,const float* be1,const float* m1,const float* v1,
    const float* W2,const float* b2,const float* g2,const float* be2,const float* m2,const float* v2,
    float* wf){
  int t = threadIdx.x;
  if (t < 64){
    float s = g0[t]/sqrtf(v0[t]+1e-5f);
    wf[B0F+t] = (b0[t]-m0[t])*s + be0[t];
    for (int c=0;c<9;c++) wf[W0T + c*64 + t] = W0[t*9+c]*s;
    float s1 = g1[t]/sqrtf(v1[t]+1e-5f);
    wf[B1F+t] = (b1[t]-m1[t])*s1 + be1[t];
    for (int c=0;c<64;c++) wf[W1T + c*64 + t] = W1[t*64+c]*s1;
  }
  if (t < 128){
    float s2 = g2[t]/sqrtf(v2[t]+1e-5f);
    wf[B2F+t] = (b2[t]-m2[t])*s2 + be2[t];
    for (int c=0;c<64;c++) wf[W2T + c*128 + t] = W2[t*64+c]*s2;
  }
}

// ---- K2: per-point squared norms (exact ref order, no FMA) ----
__global__ __launch_bounds__(256) void k_norm(const float* xyz, float* nrm){
  int i = blockIdx.x*256 + threadIdx.x;     // < BB*NN
  int b = i >> 12, n = i & (NN-1);
  const float* X = xyz + (size_t)b*3*NN;
  float x=X[n], y=X[NN+n], z=X[2*NN+n];
  nrm[i] = __fadd_rn(__fadd_rn(__fmul_rn(x,x),__fmul_rn(y,y)),__fmul_rn(z,z));
}

// ---- K3: farthest point sampling (exact, no-FMA distances) ----
__global__ __launch_bounds__(512) void k_fps(const float* xyz, int* fpsidx){
  __shared__ float px[NN], py[NN], pz[NN];
  __shared__ unsigned long long red[8];
  __shared__ int curs;
  int b = blockIdx.x, tid = threadIdx.x;
  const float* X = xyz + (size_t)b*3*NN;
  float lx[8], ly[8], lz[8], dist[8];
  #pragma unroll
  for (int j=0;j<8;j++){
    int p = tid + j*512;
    float x = X[p], y = X[NN+p], z = X[2*NN+p];
    px[p]=x; py[p]=y; pz[p]=z;
    lx[j]=x; ly[j]=y; lz[j]=z; dist[j]=1e10f;
  }
  if (tid==0) fpsidx[b*SS] = 0;
  __syncthreads();
  int cur = 0;
  for (int t=1;t<SS;t++){
    float cx=px[cur], cy=py[cur], cz=pz[cur];
    float bv = -1.0f; int bi = 0;
    #pragma unroll
    for (int j=0;j<8;j++){
      float dx=__fsub_rn(lx[j],cx), dy=__fsub_rn(ly[j],cy), dz=__fsub_rn(lz[j],cz);
      float d = __fadd_rn(__fadd_rn(__fmul_rn(dx,dx),__fmul_rn(dy,dy)),__fmul_rn(dz,dz));
      float nd = fminf(dist[j], d);
      dist[j] = nd;
      if (nd > bv){ bv = nd; bi = tid + j*512; }   // strict > keeps smallest p in-thread
    }
    // pack: larger dist wins; tie -> smaller index wins (argmax-first semantics)
    unsigned long long key = ((unsigned long long)__float_as_uint(bv) << 32)
                           | (unsigned long long)(0xFFFFFFFFu - (unsigned)bi);
    { unsigned long long o;
      o = sx64(key,1);  if (o>key) key=o;
      o = sx64(key,2);  if (o>key) key=o;
      o = sx64(key,4);  if (o>key) key=o;
      o = sx64(key,8);  if (o>key) key=o;
      o = sx64(key,16); if (o>key) key=o;
      o = sx64(key,32); if (o>key) key=o; }
    if ((tid&63)==0) red[tid>>6] = key;
    __syncthreads();
    if (tid < 8){
      unsigned long long v = red[tid], o;
      o = sx64(v,1); if (o>v) v=o;
      o = sx64(v,2); if (o>v) v=o;
      o = sx64(v,4); if (o>v) v=o;
      if (tid==0){
        int idx = (int)(0xFFFFFFFFu - (unsigned)(v & 0xFFFFFFFFull));
        curs = idx; fpsidx[b*SS+t] = idx;
      }
    }
    __syncthreads();
    cur = curs;
  }
}

// ---- K4: ball query (exact -2*dot+|s|^2+|d|^2, FMA dot, f32(0.04) radius) ----
__global__ __launch_bounds__(256) void k_ball(const float* xyz, const float* points, const float* nrm,
                                              const int* fpsidx, int* gidx, float* fpin, float* out0){
  int wid = threadIdx.x >> 6, lane = threadIdx.x & 63;
  int s = blockIdx.x*4 + wid;
  int b = s >> 10, si = s & (SS-1);
  const float* X = xyz + (size_t)b*3*NN;
  int cidx = fpsidx[s];
  float sx = X[cidx], sy = X[NN+cidx], sz = X[2*NN+cidx];
  float sn = nrm[b*NN + cidx];
  if (lane < 3){
    float v = lane==0?sx:(lane==1?sy:sz);
    fpin[s*9+lane] = v;
    out0[b*3*SS + lane*SS + si] = v;
  } else if (lane < 9){
    fpin[s*9+lane] = points[(size_t)b*6*NN + (size_t)(lane-3)*NN + cidx];
  }
  const float R2 = (float)(0.2*0.2);   // double 0.04 -> f32
  int total = 0; int first = 0;
  for (int ch=0; ch<NN/64; ch++){
    int n = ch*64 + lane;
    float pxv=X[n], pyv=X[NN+n], pzv=X[2*NN+n];
    float dot = __fmaf_rn(sz,pzv, __fmaf_rn(sy,pyv, __fmul_rn(sx,pxv)));
    float sqr = __fadd_rn(__fadd_rn(__fmul_rn(-2.0f,dot), sn), nrm[b*NN+n]);
    bool inc = (sqr <= R2);
    unsigned long long mask = __ballot(inc);
    if (total == 0 && mask != 0ull) first = ch*64 + (__ffsll((long long)mask) - 1);
    if (inc){
      int pos = total + __popcll(mask & ((1ull<<lane)-1ull));
      if (pos < KNB) gidx[s*KNB + pos] = n;
    }
    total += (int)__popcll(mask);
    if (total >= KNB) break;
  }
  if (total < KNB && lane >= total && lane < KNB) gidx[s*KNB + lane] = first;
}

// ---- K5: fused gather + 3-layer MLP (both branches) + attention pool ----
__global__ __launch_bounds__(256) void k_fused(const float* xyz, const float* points, const float* am,
                                               const float* wf, const int* gidx, const float* fpin,
                                               float* out1){
  __shared__ float fin[9];
  __shared__ float Hf1[64], Hf2[64], F3[128];
  __shared__ float in9[32][13];
  __shared__ float H1[32][68];
  __shared__ float H2[32][68];
  __shared__ float DNP[32][132];
  int s = blockIdx.x; int b = s >> 10; int si = s & (SS-1);
  int tid = threadIdx.x; int k = tid & 31; int fg = tid >> 5;

  if (tid < 9) fin[tid] = fpin[s*9 + tid];
  __syncthreads();

  // fps branch L0 (threads 0-63) + neighbor gather (threads 64-95)
  if (tid < 64){
    float acc = wf[B0F + tid];
    #pragma unroll
    for (int c=0;c<9;c++) acc = fmaf(fin[c], wf[W0T + c*64 + tid], acc);
    Hf1[tid] = fmaxf(acc, 0.0f);
  } else if (tid < 96){
    int kk = tid - 64;
    int ki = gidx[s*KNB + kk];
    const float* X = xyz + (size_t)b*3*NN;
    in9[kk][0] = X[ki]        - fin[0];
    in9[kk][1] = X[NN+ki]     - fin[1];
    in9[kk][2] = X[2*NN+ki]   - fin[2];
    const float* P = points + (size_t)b*6*NN;
    #pragma unroll
    for (int c=0;c<6;c++) in9[kk][3+c] = P[(size_t)c*NN + ki];
  }
  __syncthreads();
  if (tid < 64){
    float acc = wf[B1F + tid];
    for (int c=0;c<64;c++) acc = fmaf(Hf1[c], wf[W1T + c*64 + tid], acc);
    Hf2[tid] = fmaxf(acc, 0.0f);
  }
  __syncthreads();
  if (tid < 128){
    float acc = wf[B2F + tid];
    for (int c=0;c<64;c++) acc = fmaf(Hf2[c], wf[W2T + c*128 + tid], acc);
    F3[tid] = fmaxf(acc, 0.0f);
  }
  __syncthreads();

  // main L0: 9 -> 64
  {
    int f0 = fg*8;
    float h[8];
    { float4 q0=LDQ(wf+B0F+f0), q1=LDQ(wf+B0F+f0+4);
      h[0]=q0.x; h[1]=q0.y; h[2]=q0.z; h[3]=q0.w; h[4]=q1.x; h[5]=q1.y; h[6]=q1.z; h[7]=q1.w; }
    #pragma unroll
    for (int c=0;c<9;c++){
      fma8(h, in9[k][c], wf + W0T + c*64 + f0);
    }
    float4 o0, o1;
    o0.x=fmaxf(h[0],0.f); o0.y=fmaxf(h[1],0.f); o0.z=fmaxf(h[2],0.f); o0.w=fmaxf(h[3],0.f);
    o1.x=fmaxf(h[4],0.f); o1.y=fmaxf(h[5],0.f); o1.z=fmaxf(h[6],0.f); o1.w=fmaxf(h[7],0.f);
    *(float4*)&H1[k][f0] = o0; *(float4*)&H1[k][f0+4] = o1;
  }
  __syncthreads();

  // main L1: 64 -> 64
  {
    int f0 = fg*8;
    float h[8];
    { float4 q0=LDQ(wf+B1F+f0), q1=LDQ(wf+B1F+f0+4);
      h[0]=q0.x; h[1]=q0.y; h[2]=q0.z; h[3]=q0.w; h[4]=q1.x; h[5]=q1.y; h[6]=q1.z; h[7]=q1.w; }
    for (int c4=0;c4<16;c4++){
      float4 hv = *(const float4*)&H1[k][c4*4];
      const float* wr = wf + W1T + c4*4*64 + f0;
      fma8(h, hv.x, wr); fma8(h, hv.y, wr+64); fma8(h, hv.z, wr+128); fma8(h, hv.w, wr+192);
    }
    float4 o0, o1;
    o0.x=fmaxf(h[0],0.f); o0.y=fmaxf(h[1],0.f); o0.z=fmaxf(h[2],0.f); o0.w=fmaxf(h[3],0.f);
    o1.x=fmaxf(h[4],0.f); o1.y=fmaxf(h[5],0.f); o1.z=fmaxf(h[6],0.f); o1.w=fmaxf(h[7],0.f);
    *(float4*)&H2[k][f0] = o0; *(float4*)&H2[k][f0+4] = o1;
  }
  __syncthreads();

  // main L2: 64 -> 128 ; keep np in regs, write DNP = np - F3
  float np[16];
  {
    int f0 = fg*16;
    { float4 q;
      q=LDQ(wf+B2F+f0);    np[0]=q.x;  np[1]=q.y;  np[2]=q.z;  np[3]=q.w;
      q=LDQ(wf+B2F+f0+4);  np[4]=q.x;  np[5]=q.y;  np[6]=q.z;  np[7]=q.w;
      q=LDQ(wf+B2F+f0+8);  np[8]=q.x;  np[9]=q.y;  np[10]=q.z; np[11]=q.w;
      q=LDQ(wf+B2F+f0+12); np[12]=q.x; np[13]=q.y; np[14]=q.z; np[15]=q.w; }
    for (int c4=0;c4<16;c4++){
      float4 hv = *(const float4*)&H2[k][c4*4];
      const float* wr = wf + W2T + c4*4*128 + f0;
      fma16(np, hv.x, wr); fma16(np, hv.y, wr+128); fma16(np, hv.z, wr+256); fma16(np, hv.w, wr+384);
    }
    #pragma unroll
    for (int j=0;j<16;j++) np[j] = fmaxf(np[j], 0.0f);
    #pragma unroll
    for (int jq=0;jq<4;jq++){
      float4 f3 = *(const float4*)&F3[f0+jq*4];
      float4 o;
      o.x = np[jq*4+0]-f3.x; o.y = np[jq*4+1]-f3.y; o.z = np[jq*4+2]-f3.z; o.w = np[jq*4+3]-f3.w;
      *(float4*)&DNP[k][f0+jq*4] = o;
    }
  }
  __syncthreads();

  // attention: e = dp . a[0:3] - DNP . a[3:131]; leaky; softmax over k; pool
  {
    int f0 = fg*16;
    float dp0=-in9[k][0], dp1=-in9[k][1], dp2=-in9[k][2];
    float e[16];
    #pragma unroll
    for (int jq=0;jq<4;jq++){
      float4 a0=LDQ(am + f0 + jq*4);
      float4 a1=LDQ(am + 128 + f0 + jq*4);
      float4 a2=LDQ(am + 256 + f0 + jq*4);
      e[jq*4+0]=fmaf(dp2,a2.x,fmaf(dp1,a1.x,dp0*a0.x));
      e[jq*4+1]=fmaf(dp2,a2.y,fmaf(dp1,a1.y,dp0*a0.y));
      e[jq*4+2]=fmaf(dp2,a2.z,fmaf(dp1,a1.z,dp0*a0.z));
      e[jq*4+3]=fmaf(dp2,a2.w,fmaf(dp1,a1.w,dp0*a0.w));
    }
    for (int c4=0;c4<32;c4++){
      float4 hv = *(const float4*)&DNP[k][c4*4];
      const float* wr = am + (3 + c4*4)*128 + f0;
      fma16(e, -hv.x, wr); fma16(e, -hv.y, wr+128); fma16(e, -hv.z, wr+256); fma16(e, -hv.w, wr+384);
    }
    size_t ob = (size_t)b*128*SS + si;
    #pragma unroll
    for (int j=0;j<16;j++){
      float ej = e[j]; ej = (ej >= 0.0f) ? ej : 0.2f*ej;
      float mx = ej;
      mx = fmaxf(mx, __shfl_xor(mx,1));
      mx = fmaxf(mx, __shfl_xor(mx,2));
      mx = fmaxf(mx, __shfl_xor(mx,4));
      mx = fmaxf(mx, __shfl_xor(mx,8));
      mx = fmaxf(mx, __shfl_xor(mx,16));
      float p = __expf(ej - mx);
      float sm = p;
      sm += __shfl_xor(sm,1); sm += __shfl_xor(sm,2); sm += __shfl_xor(sm,4);
      sm += __shfl_xor(sm,8); sm += __shfl_xor(sm,16);
      float po = (p / sm) * np[j];
      po += __shfl_xor(po,1); po += __shfl_xor(po,2); po += __shfl_xor(po,4);
      po += __shfl_xor(po,8); po += __shfl_xor(po,16);
      if (k == 0) out1[ob + (size_t)(f0+j)*SS] = po;
    }
  }
}

extern "C" void kernel_launch(void* const* d_in, const int* in_sizes, int n_in,
                              void* d_out, int out_size, void* d_ws, size_t ws_size,
                              hipStream_t stream){
  (void)in_sizes; (void)n_in; (void)out_size; (void)ws_size;
  const float* xyz    = (const float*)d_in[0];
  const float* points = (const float*)d_in[1];
  const float* am     = (const float*)d_in[20];
  float* ws  = (float*)d_ws;
  int*   fpsidx = (int*)d_ws + FPSIDX_OFF;
  int*   gidx   = (int*)d_ws + GIDX_OFF;
  float* nrm    = ws + NORM_OFF;
  float* fpin   = ws + FPIN_OFF;
  float* wf     = ws + WF_OFF;
  float* out0   = (float*)d_out;
  float* out1   = (float*)d_out + BB*3*SS;

  k_fold<<<1,128,0,stream>>>(
      (const float*)d_in[2],(const float*)d_in[3],(const float*)d_in[4],(const float*)d_in[5],(const float*)d_in[6],(const float*)d_in[7],
      (const float*)d_in[8],(const float*)d_in[9],(const float*)d_in[10],(const float*)d_in[11],(const float*)d_in[12],(const float*)d_in[13],
      (const float*)d_in[14],(const float*)d_in[15],(const float*)d_in[16],(const float*)d_in[17],(const float*)d_in[18],(const float*)d_in[19],
      wf);
  k_norm<<<BB*NN/256,256,0,stream>>>(xyz, nrm);
  k_fps<<<BB,512,0,stream>>>(xyz, fpsidx);
  k_ball<<<BB*SS/4,256,0,stream>>>(xyz, points, nrm, fpsidx, gidx, fpin, out0);
  k_fused<<<BB*SS,256,0,stream>>>(xyz, points, am, wf, gidx, fpin, out1);
}

// Round 3
// 1342.943 us; speedup vs baseline: 1.9459x; 1.9459x over previous
//
#include <hip/hip_runtime.h>

#define BB 16
#define NN 4096
#define SS 1024
#define KNB 32

// ---- ws layout (in 4-byte words) ----
#define FPSIDX_OFF 0                         // int[BB*SS]
#define GIDX_OFF   (BB*SS)                   // int[BB*SS*KNB]
#define NORM_OFF   (GIDX_OFF + BB*SS*KNB)    // float[BB*NN]
#define FPIN_OFF   (NORM_OFF + BB*NN)        // float[BB*SS*9]
#define WF_OFF     (FPIN_OFF + BB*SS*9)      // float[13120]

// folded-weight layout (floats, within wf)
#define W0T 0          // [9][64]
#define B0F 576
#define W1T 640        // [64][64]
#define B1F 4736
#define W2T 4800       // [64][128]
#define B2F 12992

__device__ __forceinline__ unsigned long long sx64(unsigned long long v, int m){
  unsigned lo = __shfl_xor((unsigned)v, m);
  unsigned hi = __shfl_xor((unsigned)(v>>32), m);
  return ((unsigned long long)hi<<32) | lo;
}

// ---- K1: fold BN into weights, transpose to [c][f] ----
__global__ __launch_bounds__(128) void k_fold(
    const float* W0,const float* b0,const float* g0,const float* be0,const float* m0,const float* v0,
    const float* W1,const float* b1,const float* g1,const float* be1,const float* m1,const float* v1,
    const float* W2,const float* b2,const float* g2,const float* be2,const float* m2,const float* v2,
    float* wf){
  int t = threadIdx.x;
  if (t < 64){
    float s = g0[t]/sqrtf(v0[t]+1e-5f);
    wf[B0F+t] = (b0[t]-m0[t])*s + be0[t];
    for (int c=0;c<9;c++) wf[W0T + c*64 + t] = W0[t*9+c]*s;
    float s1 = g1[t]/sqrtf(v1[t]+1e-5f);
    wf[B1F+t] = (b1[t]-m1[t])*s1 + be1[t];
    for (int c=0;c<64;c++) wf[W1T + c*64 + t] = W1[t*64+c]*s1;
  }
  if (t < 128){
    float s2 = g2[t]/sqrtf(v2[t]+1e-5f);
    wf[B2F+t] = (b2[t]-m2[t])*s2 + be2[t];
    for (int c=0;c<64;c++) wf[W2T + c*128 + t] = W2[t*64+c]*s2;
  }
}

// ---- K2: per-point squared norms (exact ref order, no FMA) ----
__global__ __launch_bounds__(256) void k_norm(const float* xyz, float* nrm){
  int i = blockIdx.x*256 + threadIdx.x;     // < BB*NN
  int b = i >> 12, n = i & (NN-1);
  const float* X = xyz + (size_t)b*3*NN;
  float x=X[n], y=X[NN+n], z=X[2*NN+n];
  nrm[i] = __fadd_rn(__fadd_rn(__fmul_rn(x,x),__fmul_rn(y,y)),__fmul_rn(z,z));
}

// ---- K3: farthest point sampling (exact, no-FMA distances) ----
// single barrier/iter: double-buffered per-wave reduction slots + redundant
// cross-wave mini-reduce in every thread (same max, same tie-break).
__global__ __launch_bounds__(512) void k_fps(const float* xyz, int* fpsidx){
  __shared__ float px[NN], py[NN], pz[NN];
  __shared__ unsigned long long red[2][8];
  int b = blockIdx.x, tid = threadIdx.x;
  int w = tid >> 6, lane = tid & 63;
  const float* X = xyz + (size_t)b*3*NN;
  float lx[8], ly[8], lz[8], dist[8];
  #pragma unroll
  for (int j=0;j<8;j++){
    int p = tid + j*512;
    float x = X[p], y = X[NN+p], z = X[2*NN+p];
    px[p]=x; py[p]=y; pz[p]=z;
    lx[j]=x; ly[j]=y; lz[j]=z; dist[j]=1e10f;
  }
  if (tid==0) fpsidx[b*SS] = 0;
  __syncthreads();
  int cur = 0;
  for (int t=1;t<SS;t++){
    float cx=px[cur], cy=py[cur], cz=pz[cur];
    float bv = -1.0f; int bi = 0;
    #pragma unroll
    for (int j=0;j<8;j++){
      float dx=__fsub_rn(lx[j],cx), dy=__fsub_rn(ly[j],cy), dz=__fsub_rn(lz[j],cz);
      float d = __fadd_rn(__fadd_rn(__fmul_rn(dx,dx),__fmul_rn(dy,dy)),__fmul_rn(dz,dz));
      float nd = fminf(dist[j], d);
      dist[j] = nd;
      if (nd > bv){ bv = nd; bi = tid + j*512; }
    }
    // pack: larger dist wins; tie -> smaller index wins
    unsigned long long key = ((unsigned long long)__float_as_uint(bv) << 32)
                           | (unsigned long long)(0xFFFFFFFFu - (unsigned)bi);
    { unsigned long long o;
      o = sx64(key,1);  if (o>key) key=o;
      o = sx64(key,2);  if (o>key) key=o;
      o = sx64(key,4);  if (o>key) key=o;
      o = sx64(key,8);  if (o>key) key=o;
      o = sx64(key,16); if (o>key) key=o;
      o = sx64(key,32); if (o>key) key=o; }
    if (lane==0) red[t&1][w] = key;
    __syncthreads();
    unsigned long long v = red[t&1][lane & 7];
    { unsigned long long o;
      o = sx64(v,1); if (o>v) v=o;
      o = sx64(v,2); if (o>v) v=o;
      o = sx64(v,4); if (o>v) v=o; }
    cur = (int)(0xFFFFFFFFu - (unsigned)(v & 0xFFFFFFFFull));
    if (tid==0) fpsidx[b*SS+t] = cur;
  }
}

// ---- K4: ball query (unchanged, known-correct) ----
__global__ __launch_bounds__(256) void k_ball(const float* xyz, const float* points, const float* nrm,
                                              const int* fpsidx, int* gidx, float* fpin, float* out0){
  int wid = threadIdx.x >> 6, lane = threadIdx.x & 63;
  int s = blockIdx.x*4 + wid;
  int b = s >> 10, si = s & (SS-1);
  const float* X = xyz + (size_t)b*3*NN;
  int cidx = fpsidx[s];
  float sx = X[cidx], sy = X[NN+cidx], sz = X[2*NN+cidx];
  float sn = nrm[b*NN + cidx];
  if (lane < 3){
    float v = lane==0?sx:(lane==1?sy:sz);
    fpin[s*9+lane] = v;
    out0[b*3*SS + lane*SS + si] = v;
  } else if (lane < 9){
    fpin[s*9+lane] = points[(size_t)b*6*NN + (size_t)(lane-3)*NN + cidx];
  }
  const float R2 = (float)(0.2*0.2);
  int total = 0; int first = 0;
  for (int ch=0; ch<NN/64; ch++){
    int n = ch*64 + lane;
    float pxv=X[n], pyv=X[NN+n], pzv=X[2*NN+n];
    float dot = __fmaf_rn(sz,pzv, __fmaf_rn(sy,pyv, __fmul_rn(sx,pxv)));
    float sqr = __fadd_rn(__fadd_rn(__fmul_rn(-2.0f,dot), sn), nrm[b*NN+n]);
    bool inc = (sqr <= R2);
    unsigned long long mask = __ballot(inc);
    if (total == 0 && mask != 0ull) first = ch*64 + (__ffsll((long long)mask) - 1);
    if (inc){
      int pos = total + __popcll(mask & ((1ull<<lane)-1ull));
      if (pos < KNB) gidx[s*KNB + pos] = n;
    }
    total += (int)__popcll(mask);
    if (total >= KNB) break;
  }
  if (total < KNB && lane >= total && lane < KNB) gidx[s*KNB + lane] = first;
}

// ---- K5: fused, scalar-broadcast weights ----
// block = 256 thr = 4 waves, processes 2 centers.
// wave wv owns a feature slice; weight addrs are wave-uniform -> s_load.
// lane = (ctr<<5)|k : per-neighbor row; H/DNP in LDS with padded strides.
__global__ __launch_bounds__(256) void k_fused(const float* __restrict__ xyz,
                                               const float* __restrict__ points,
                                               const float* __restrict__ am,
                                               const float* __restrict__ wf,
                                               const int* __restrict__ gidx,
                                               const float* __restrict__ fpin,
                                               float* __restrict__ out1){
  __shared__ float smem[64*68*2];             // H1 | H2, later overlaid by DNP[64][132]
  __shared__ float Hf1[2][64], Hf2[2][64], F3l[2][128];
  float* H1  = smem;
  float* H2  = smem + 64*68;
  float* DNP = smem;

  int tid  = threadIdx.x;
  int lane = tid & 63;
  int k    = lane & 31;
  int ctr  = lane >> 5;
  int wv   = __builtin_amdgcn_readfirstlane(tid >> 6);   // uniform wave id
  int s0   = blockIdx.x*2;
  int s    = s0 + ctr;
  int b    = s >> 10;
  int si   = s & (SS-1);
  int row  = lane;

  // ---- gather own neighbor row into registers ----
  int ki = gidx[s*KNB + k];
  const float* X = xyz + (size_t)b*3*NN;
  const float* P = points + (size_t)b*6*NN;
  float fin0 = fpin[s*9+0], fin1 = fpin[s*9+1], fin2 = fpin[s*9+2];
  float gx0 = X[ki]      - fin0;
  float gx1 = X[NN+ki]   - fin1;
  float gx2 = X[2*NN+ki] - fin2;
  float g3 = P[ki], g4 = P[NN+ki], g5 = P[2*NN+ki];
  float g6 = P[3*NN+ki], g7 = P[4*NN+ki], g8 = P[5*NN+ki];

  // ---- main L0: 9 -> 64, wave slice f0 = wv*16 ----
  {
    int f0 = wv*16;
    float acc[16];
    #pragma unroll
    for (int j=0;j<16;j++) acc[j] = wf[B0F + f0 + j];
    #pragma unroll
    for (int c=0;c<9;c++){
      float xv = (c==0)?gx0:(c==1)?gx1:(c==2)?gx2:(c==3)?g3:(c==4)?g4:(c==5)?g5:(c==6)?g6:(c==7)?g7:g8;
      const float* wr = wf + W0T + c*64 + f0;
      #pragma unroll
      for (int j=0;j<16;j++) acc[j] = fmaf(xv, wr[j], acc[j]);
    }
    #pragma unroll
    for (int j=0;j<16;j+=4){
      float4 o; o.x=fmaxf(acc[j],0.f); o.y=fmaxf(acc[j+1],0.f);
      o.z=fmaxf(acc[j+2],0.f); o.w=fmaxf(acc[j+3],0.f);
      *(float4*)&H1[row*68 + f0 + j] = o;
    }
  }
  // fps-branch L0 (coalesced per-f weight reads)
  if (tid < 128){
    int f = tid & 63; int cf = tid >> 6;
    int sf = s0 + cf;
    float acc = wf[B0F + f];
    #pragma unroll
    for (int c=0;c<9;c++) acc = fmaf(fpin[sf*9+c], wf[W0T + c*64 + f], acc);
    Hf1[cf][f] = fmaxf(acc, 0.0f);
  }
  __syncthreads();

  // ---- main L1: 64 -> 64 ----
  {
    int f0 = wv*16;
    float acc[16];
    #pragma unroll
    for (int j=0;j<16;j++) acc[j] = wf[B1F + f0 + j];
    #pragma unroll 8
    for (int c4=0;c4<16;c4++){
      float4 hv = *(const float4*)&H1[row*68 + c4*4];
      const float* wr = wf + W1T + c4*4*64 + f0;
      #pragma unroll
      for (int j=0;j<16;j++) acc[j] = fmaf(hv.x, wr[j],     acc[j]);
      #pragma unroll
      for (int j=0;j<16;j++) acc[j] = fmaf(hv.y, wr[64+j],  acc[j]);
      #pragma unroll
      for (int j=0;j<16;j++) acc[j] = fmaf(hv.z, wr[128+j], acc[j]);
      #pragma unroll
      for (int j=0;j<16;j++) acc[j] = fmaf(hv.w, wr[192+j], acc[j]);
    }
    #pragma unroll
    for (int j=0;j<16;j+=4){
      float4 o; o.x=fmaxf(acc[j],0.f); o.y=fmaxf(acc[j+1],0.f);
      o.z=fmaxf(acc[j+2],0.f); o.w=fmaxf(acc[j+3],0.f);
      *(float4*)&H2[row*68 + f0 + j] = o;
    }
  }
  if (tid < 128){
    int f = tid & 63; int cf = tid >> 6;
    float acc = wf[B1F + f];
    #pragma unroll 16
    for (int c=0;c<64;c++) acc = fmaf(Hf1[cf][c], wf[W1T + c*64 + f], acc);
    Hf2[cf][f] = fmaxf(acc, 0.0f);
  }
  __syncthreads();

  // ---- main L2: 64 -> 128, np kept in regs ----
  float np[32];
  {
    int f0 = wv*32;
    #pragma unroll
    for (int j=0;j<32;j++) np[j] = wf[B2F + f0 + j];
    #pragma unroll 4
    for (int c4=0;c4<16;c4++){
      float4 hv = *(const float4*)&H2[row*68 + c4*4];
      const float* wr = wf + W2T + c4*4*128 + f0;
      #pragma unroll
      for (int j=0;j<32;j++) np[j] = fmaf(hv.x, wr[j],     np[j]);
      #pragma unroll
      for (int j=0;j<32;j++) np[j] = fmaf(hv.y, wr[128+j], np[j]);
      #pragma unroll
      for (int j=0;j<32;j++) np[j] = fmaf(hv.z, wr[256+j], np[j]);
      #pragma unroll
      for (int j=0;j<32;j++) np[j] = fmaf(hv.w, wr[384+j], np[j]);
    }
    #pragma unroll
    for (int j=0;j<32;j++) np[j] = fmaxf(np[j], 0.0f);
  }
  // fps-branch L2: all 256 threads, f = tid&127
  {
    int f = tid & 127; int cf = tid >> 7;
    float acc = wf[B2F + f];
    #pragma unroll 16
    for (int c=0;c<64;c++) acc = fmaf(Hf2[cf][c], wf[W2T + c*128 + f], acc);
    F3l[cf][f] = fmaxf(acc, 0.0f);
  }
  __syncthreads();          // all H2 reads done; F3l visible

  // ---- DNP = F3 - np (overlays H1/H2) ----
  {
    int f0 = wv*32;
    #pragma unroll
    for (int j=0;j<32;j+=4){
      float4 d;
      d.x = F3l[ctr][f0+j]   - np[j];
      d.y = F3l[ctr][f0+j+1] - np[j+1];
      d.z = F3l[ctr][f0+j+2] - np[j+2];
      d.w = F3l[ctr][f0+j+3] - np[j+3];
      *(float4*)&DNP[row*132 + f0 + j] = d;
    }
  }
  __syncthreads();

  // ---- attention + softmax + pool ----
  {
    float dp0 = -gx0, dp1 = -gx1, dp2 = -gx2;
    size_t ob = (size_t)b*128*SS + si;
    #pragma unroll
    for (int p=0;p<4;p++){
      int f0 = wv*32 + p*8;
      float e[8];
      const float* a0 = am + f0;
      #pragma unroll
      for (int j=0;j<8;j++)
        e[j] = fmaf(dp2, a0[256+j], fmaf(dp1, a0[128+j], dp0*a0[j]));
      #pragma unroll 4
      for (int c4=0;c4<32;c4++){
        float4 dv = *(const float4*)&DNP[row*132 + c4*4];
        const float* wr = am + (3 + c4*4)*128 + f0;
        #pragma unroll
        for (int j=0;j<8;j++) e[j] = fmaf(dv.x, wr[j],     e[j]);
        #pragma unroll
        for (int j=0;j<8;j++) e[j] = fmaf(dv.y, wr[128+j], e[j]);
        #pragma unroll
        for (int j=0;j<8;j++) e[j] = fmaf(dv.z, wr[256+j], e[j]);
        #pragma unroll
        for (int j=0;j<8;j++) e[j] = fmaf(dv.w, wr[384+j], e[j]);
      }
      #pragma unroll
      for (int j=0;j<8;j++){
        float ej = e[j]; ej = (ej >= 0.0f) ? ej : 0.2f*ej;
        float mx = ej;
        mx = fmaxf(mx, __shfl_xor(mx,1));
        mx = fmaxf(mx, __shfl_xor(mx,2));
        mx = fmaxf(mx, __shfl_xor(mx,4));
        mx = fmaxf(mx, __shfl_xor(mx,8));
        mx = fmaxf(mx, __shfl_xor(mx,16));
        float pp = __expf(ej - mx);
        float sm = pp;
        sm += __shfl_xor(sm,1); sm += __shfl_xor(sm,2); sm += __shfl_xor(sm,4);
        sm += __shfl_xor(sm,8); sm += __shfl_xor(sm,16);
        float po = (pp / sm) * np[p*8+j];
        po += __shfl_xor(po,1); po += __shfl_xor(po,2); po += __shfl_xor(po,4);
        po += __shfl_xor(po,8); po += __shfl_xor(po,16);
        if (k == 0) out1[ob + (size_t)(f0+j)*SS] = po;
      }
    }
  }
}

extern "C" void kernel_launch(void* const* d_in, const int* in_sizes, int n_in,
                              void* d_out, int out_size, void* d_ws, size_t ws_size,
                              hipStream_t stream){
  (void)in_sizes; (void)n_in; (void)out_size; (void)ws_size;
  const float* xyz    = (const float*)d_in[0];
  const float* points = (const float*)d_in[1];
  const float* am     = (const float*)d_in[20];
  float* ws  = (float*)d_ws;
  int*   fpsidx = (int*)d_ws + FPSIDX_OFF;
  int*   gidx   = (int*)d_ws + GIDX_OFF;
  float* nrm    = ws + NORM_OFF;
  float* fpin   = ws + FPIN_OFF;
  float* wf     = ws + WF_OFF;
  float* out0   = (float*)d_out;
  float* out1   = (float*)d_out + BB*3*SS;

  k_fold<<<1,128,0,stream>>>(
      (const float*)d_in[2],(const float*)d_in[3],(const float*)d_in[4],(const float*)d_in[5],(const float*)d_in[6],(const float*)d_in[7],
      (const float*)d_in[8],(const float*)d_in[9],(const float*)d_in[10],(const float*)d_in[11],(const float*)d_in[12],(const float*)d_in[13],
      (const float*)d_in[14],(const float*)d_in[15],(const float*)d_in[16],(const float*)d_in[17],(const float*)d_in[18],(const float*)d_in[19],
      wf);
  k_norm<<<BB*NN/256,256,0,stream>>>(xyz, nrm);
  k_fps<<<BB,512,0,stream>>>(xyz, fpsidx);
  k_ball<<<BB*SS/4,256,0,stream>>>(xyz, points, nrm, fpsidx, gidx, fpin, out0);
  k_fused<<<BB*SS/2,256,0,stream>>>(xyz, points, am, wf, gidx, fpin, out1);
}

// Round 4
// 1107.758 us; speedup vs baseline: 2.3590x; 1.2123x over previous
//
#include <hip/hip_runtime.h>

#define BB 16
#define NN 4096
#define SS 1024
#define KNB 32

// ---- ws layout (in 4-byte words) ----
#define FPSIDX_OFF 0                         // int[BB*SS]
#define GIDX_OFF   (BB*SS)                   // int[BB*SS*KNB]
#define NORM_OFF   (GIDX_OFF + BB*SS*KNB)    // float[BB*NN]
#define FPIN_OFF   (NORM_OFF + BB*NN)        // float[BB*SS*9]
#define WF_OFF     (FPIN_OFF + BB*SS*9)      // float[13120]

// folded-weight layout (floats, within wf)
#define W0T 0          // [9][64]
#define B0F 576
#define W1T 640        // [64][64]
#define B1F 4736
#define W2T 4800       // [64][128]
#define B2F 12992

// ---- K1: fold BN into weights, transpose to [c][f] ----
__global__ __launch_bounds__(128) void k_fold(
    const float* W0,const float* b0,const float* g0,const float* be0,const float* m0,const float* v0,
    const float* W1,const float* b1,const float* g1,const float* be1,const float* m1,const float* v1,
    const float* W2,const float* b2,const float* g2,const float* be2,const float* m2,const float* v2,
    float* wf){
  int t = threadIdx.x;
  if (t < 64){
    float s = g0[t]/sqrtf(v0[t]+1e-5f);
    wf[B0F+t] = (b0[t]-m0[t])*s + be0[t];
    for (int c=0;c<9;c++) wf[W0T + c*64 + t] = W0[t*9+c]*s;
    float s1 = g1[t]/sqrtf(v1[t]+1e-5f);
    wf[B1F+t] = (b1[t]-m1[t])*s1 + be1[t];
    for (int c=0;c<64;c++) wf[W1T + c*64 + t] = W1[t*64+c]*s1;
  }
  if (t < 128){
    float s2 = g2[t]/sqrtf(v2[t]+1e-5f);
    wf[B2F+t] = (b2[t]-m2[t])*s2 + be2[t];
    for (int c=0;c<64;c++) wf[W2T + c*128 + t] = W2[t*64+c]*s2;
  }
}

// ---- K2: per-point squared norms (exact ref order, no FMA) ----
__global__ __launch_bounds__(256) void k_norm(const float* xyz, float* nrm){
  int i = blockIdx.x*256 + threadIdx.x;     // < BB*NN
  int b = i >> 12, n = i & (NN-1);
  const float* X = xyz + (size_t)b*3*NN;
  float x=X[n], y=X[NN+n], z=X[2*NN+n];
  nrm[i] = __fadd_rn(__fadd_rn(__fmul_rn(x,x),__fmul_rn(y,y)),__fmul_rn(z,z));
}

// ---- K3: farthest point sampling ----
// 256 thr (4 waves), 16 pts/thread. Wave argmax via DPP max-reduce on a
// packed u64 key (dist_bits<<32 | ~index) -> VALU latency, no bpermute.
// Cross-wave: lane63's key readlane'd, lane0 writes 1 u64/wave, single
// barrier/iter (double-buffered slots), 4-key unrolled scan.
template<int CTRL, int RMASK>
__device__ __forceinline__ void dpp_max_step(unsigned &lo, unsigned &hi){
  unsigned nlo = (unsigned)__builtin_amdgcn_update_dpp(0, (int)lo, CTRL, RMASK, 0xF, false);
  unsigned nhi = (unsigned)__builtin_amdgcn_update_dpp(0, (int)hi, CTRL, RMASK, 0xF, false);
  unsigned long long cand = ((unsigned long long)nhi<<32) | nlo;
  unsigned long long curk = ((unsigned long long)hi<<32)  | lo;
  if (cand > curk){ lo = nlo; hi = nhi; }
}

__global__ __launch_bounds__(256) void k_fps(const float* xyz, int* fpsidx){
  __shared__ float px[NN], py[NN], pz[NN];
  __shared__ unsigned long long red[2][4];
  int b = blockIdx.x, tid = threadIdx.x;
  int w = tid >> 6, lane = tid & 63;
  const float* X = xyz + (size_t)b*3*NN;
  float lx[16], ly[16], lz[16], dist[16];
  #pragma unroll
  for (int j=0;j<16;j++){
    int p = tid + j*256;
    float x = X[p], y = X[NN+p], z = X[2*NN+p];
    px[p]=x; py[p]=y; pz[p]=z;
    lx[j]=x; ly[j]=y; lz[j]=z; dist[j]=1e10f;
  }
  if (tid==0) fpsidx[b*SS] = 0;
  __syncthreads();
  int cur = 0;
  for (int t=1;t<SS;t++){
    float cx=px[cur], cy=py[cur], cz=pz[cur];
    float bv = -1.0f; int bj = 0;
    #pragma unroll
    for (int j=0;j<16;j++){
      float dx=__fsub_rn(lx[j],cx), dy=__fsub_rn(ly[j],cy), dz=__fsub_rn(lz[j],cz);
      float d = __fadd_rn(__fadd_rn(__fmul_rn(dx,dx),__fmul_rn(dy,dy)),__fmul_rn(dz,dz));
      float nd = fminf(dist[j], d);
      dist[j] = nd;
      bool c = nd > bv;        // strict >: first (smallest j) max kept
      bv = c ? nd : bv;
      bj = c ? j  : bj;
    }
    int bi = tid + (bj << 8);                 // global point index
    unsigned lo = 0xFFFFFFFFu - (unsigned)bi; // ~idx: smaller idx -> bigger key
    unsigned hi = __float_as_uint(bv);        // dist>=0: bits monotone
    dpp_max_step<0x111,0xF>(lo,hi);   // row_shr:1
    dpp_max_step<0x112,0xF>(lo,hi);   // row_shr:2
    dpp_max_step<0x114,0xF>(lo,hi);   // row_shr:4
    dpp_max_step<0x118,0xF>(lo,hi);   // row_shr:8
    dpp_max_step<0x142,0xA>(lo,hi);   // row_bcast:15 -> rows 1,3
    dpp_max_step<0x143,0xC>(lo,hi);   // row_bcast:31 -> rows 2,3
    unsigned glo = (unsigned)__builtin_amdgcn_readlane((int)lo, 63);
    unsigned ghi = (unsigned)__builtin_amdgcn_readlane((int)hi, 63);
    if (lane==0) red[t&1][w] = ((unsigned long long)ghi<<32) | glo;
    __syncthreads();
    unsigned long long k0 = red[t&1][0], k1 = red[t&1][1];
    unsigned long long k2 = red[t&1][2], k3 = red[t&1][3];
    unsigned long long bk = k0;
    if (k1 > bk) bk = k1;
    if (k2 > bk) bk = k2;
    if (k3 > bk) bk = k3;
    cur = (int)(0xFFFFFFFFu - (unsigned)(bk & 0xFFFFFFFFull));
    if (tid==0) fpsidx[b*SS+t] = cur;
  }
}

// ---- K4: ball query (unchanged, known-correct) ----
__global__ __launch_bounds__(256) void k_ball(const float* xyz, const float* points, const float* nrm,
                                              const int* fpsidx, int* gidx, float* fpin, float* out0){
  int wid = threadIdx.x >> 6, lane = threadIdx.x & 63;
  int s = blockIdx.x*4 + wid;
  int b = s >> 10, si = s & (SS-1);
  const float* X = xyz + (size_t)b*3*NN;
  int cidx = fpsidx[s];
  float sx = X[cidx], sy = X[NN+cidx], sz = X[2*NN+cidx];
  float sn = nrm[b*NN + cidx];
  if (lane < 3){
    float v = lane==0?sx:(lane==1?sy:sz);
    fpin[s*9+lane] = v;
    out0[b*3*SS + lane*SS + si] = v;
  } else if (lane < 9){
    fpin[s*9+lane] = points[(size_t)b*6*NN + (size_t)(lane-3)*NN + cidx];
  }
  const float R2 = (float)(0.2*0.2);
  int total = 0; int first = 0;
  for (int ch=0; ch<NN/64; ch++){
    int n = ch*64 + lane;
    float pxv=X[n], pyv=X[NN+n], pzv=X[2*NN+n];
    float dot = __fmaf_rn(sz,pzv, __fmaf_rn(sy,pyv, __fmul_rn(sx,pxv)));
    float sqr = __fadd_rn(__fadd_rn(__fmul_rn(-2.0f,dot), sn), nrm[b*NN+n]);
    bool inc = (sqr <= R2);
    unsigned long long mask = __ballot(inc);
    if (total == 0 && mask != 0ull) first = ch*64 + (__ffsll((long long)mask) - 1);
    if (inc){
      int pos = total + __popcll(mask & ((1ull<<lane)-1ull));
      if (pos < KNB) gidx[s*KNB + pos] = n;
    }
    total += (int)__popcll(mask);
    if (total >= KNB) break;
  }
  if (total < KNB && lane >= total && lane < KNB) gidx[s*KNB + lane] = first;
}

// ---- K5: fused, scalar-broadcast weights (unchanged, known-correct) ----
__global__ __launch_bounds__(256) void k_fused(const float* __restrict__ xyz,
                                               const float* __restrict__ points,
                                               const float* __restrict__ am,
                                               const float* __restrict__ wf,
                                               const int* __restrict__ gidx,
                                               const float* __restrict__ fpin,
                                               float* __restrict__ out1){
  __shared__ float smem[64*68*2];             // H1 | H2, later overlaid by DNP[64][132]
  __shared__ float Hf1[2][64], Hf2[2][64], F3l[2][128];
  float* H1  = smem;
  float* H2  = smem + 64*68;
  float* DNP = smem;

  int tid  = threadIdx.x;
  int lane = tid & 63;
  int k    = lane & 31;
  int ctr  = lane >> 5;
  int wv   = __builtin_amdgcn_readfirstlane(tid >> 6);   // uniform wave id
  int s0   = blockIdx.x*2;
  int s    = s0 + ctr;
  int b    = s >> 10;
  int si   = s & (SS-1);
  int row  = lane;

  // ---- gather own neighbor row into registers ----
  int ki = gidx[s*KNB + k];
  const float* X = xyz + (size_t)b*3*NN;
  const float* P = points + (size_t)b*6*NN;
  float fin0 = fpin[s*9+0], fin1 = fpin[s*9+1], fin2 = fpin[s*9+2];
  float gx0 = X[ki]      - fin0;
  float gx1 = X[NN+ki]   - fin1;
  float gx2 = X[2*NN+ki] - fin2;
  float g3 = P[ki], g4 = P[NN+ki], g5 = P[2*NN+ki];
  float g6 = P[3*NN+ki], g7 = P[4*NN+ki], g8 = P[5*NN+ki];

  // ---- main L0: 9 -> 64, wave slice f0 = wv*16 ----
  {
    int f0 = wv*16;
    float acc[16];
    #pragma unroll
    for (int j=0;j<16;j++) acc[j] = wf[B0F + f0 + j];
    #pragma unroll
    for (int c=0;c<9;c++){
      float xv = (c==0)?gx0:(c==1)?gx1:(c==2)?gx2:(c==3)?g3:(c==4)?g4:(c==5)?g5:(c==6)?g6:(c==7)?g7:g8;
      const float* wr = wf + W0T + c*64 + f0;
      #pragma unroll
      for (int j=0;j<16;j++) acc[j] = fmaf(xv, wr[j], acc[j]);
    }
    #pragma unroll
    for (int j=0;j<16;j+=4){
      float4 o; o.x=fmaxf(acc[j],0.f); o.y=fmaxf(acc[j+1],0.f);
      o.z=fmaxf(acc[j+2],0.f); o.w=fmaxf(acc[j+3],0.f);
      *(float4*)&H1[row*68 + f0 + j] = o;
    }
  }
  // fps-branch L0 (coalesced per-f weight reads)
  if (tid < 128){
    int f = tid & 63; int cf = tid >> 6;
    int sf = s0 + cf;
    float acc = wf[B0F + f];
    #pragma unroll
    for (int c=0;c<9;c++) acc = fmaf(fpin[sf*9+c], wf[W0T + c*64 + f], acc);
    Hf1[cf][f] = fmaxf(acc, 0.0f);
  }
  __syncthreads();

  // ---- main L1: 64 -> 64 ----
  {
    int f0 = wv*16;
    float acc[16];
    #pragma unroll
    for (int j=0;j<16;j++) acc[j] = wf[B1F + f0 + j];
    #pragma unroll 8
    for (int c4=0;c4<16;c4++){
      float4 hv = *(const float4*)&H1[row*68 + c4*4];
      const float* wr = wf + W1T + c4*4*64 + f0;
      #pragma unroll
      for (int j=0;j<16;j++) acc[j] = fmaf(hv.x, wr[j],     acc[j]);
      #pragma unroll
      for (int j=0;j<16;j++) acc[j] = fmaf(hv.y, wr[64+j],  acc[j]);
      #pragma unroll
      for (int j=0;j<16;j++) acc[j] = fmaf(hv.z, wr[128+j], acc[j]);
      #pragma unroll
      for (int j=0;j<16;j++) acc[j] = fmaf(hv.w, wr[192+j], acc[j]);
    }
    #pragma unroll
    for (int j=0;j<16;j+=4){
      float4 o; o.x=fmaxf(acc[j],0.f); o.y=fmaxf(acc[j+1],0.f);
      o.z=fmaxf(acc[j+2],0.f); o.w=fmaxf(acc[j+3],0.f);
      *(float4*)&H2[row*68 + f0 + j] = o;
    }
  }
  if (tid < 128){
    int f = tid & 63; int cf = tid >> 6;
    float acc = wf[B1F + f];
    #pragma unroll 16
    for (int c=0;c<64;c++) acc = fmaf(Hf1[cf][c], wf[W1T + c*64 + f], acc);
    Hf2[cf][f] = fmaxf(acc, 0.0f);
  }
  __syncthreads();

  // ---- main L2: 64 -> 128, np kept in regs ----
  float np[32];
  {
    int f0 = wv*32;
    #pragma unroll
    for (int j=0;j<32;j++) np[j] = wf[B2F + f0 + j];
    #pragma unroll 4
    for (int c4=0;c4<16;c4++){
      float4 hv = *(const float4*)&H2[row*68 + c4*4];
      const float* wr = wf + W2T + c4*4*128 + f0;
      #pragma unroll
      for (int j=0;j<32;j++) np[j] = fmaf(hv.x, wr[j],     np[j]);
      #pragma unroll
      for (int j=0;j<32;j++) np[j] = fmaf(hv.y, wr[128+j], np[j]);
      #pragma unroll
      for (int j=0;j<32;j++) np[j] = fmaf(hv.z, wr[256+j], np[j]);
      #pragma unroll
      for (int j=0;j<32;j++) np[j] = fmaf(hv.w, wr[384+j], np[j]);
    }
    #pragma unroll
    for (int j=0;j<32;j++) np[j] = fmaxf(np[j], 0.0f);
  }
  // fps-branch L2: all 256 threads, f = tid&127
  {
    int f = tid & 127; int cf = tid >> 7;
    float acc = wf[B2F + f];
    #pragma unroll 16
    for (int c=0;c<64;c++) acc = fmaf(Hf2[cf][c], wf[W2T + c*128 + f], acc);
    F3l[cf][f] = fmaxf(acc, 0.0f);
  }
  __syncthreads();          // all H2 reads done; F3l visible

  // ---- DNP = F3 - np (overlays H1/H2) ----
  {
    int f0 = wv*32;
    #pragma unroll
    for (int j=0;j<32;j+=4){
      float4 d;
      d.x = F3l[ctr][f0+j]   - np[j];
      d.y = F3l[ctr][f0+j+1] - np[j+1];
      d.z = F3l[ctr][f0+j+2] - np[j+2];
      d.w = F3l[ctr][f0+j+3] - np[j+3];
      *(float4*)&DNP[row*132 + f0 + j] = d;
    }
  }
  __syncthreads();

  // ---- attention + softmax + pool ----
  {
    float dp0 = -gx0, dp1 = -gx1, dp2 = -gx2;
    size_t ob = (size_t)b*128*SS + si;
    #pragma unroll
    for (int p=0;p<4;p++){
      int f0 = wv*32 + p*8;
      float e[8];
      const float* a0 = am + f0;
      #pragma unroll
      for (int j=0;j<8;j++)
        e[j] = fmaf(dp2, a0[256+j], fmaf(dp1, a0[128+j], dp0*a0[j]));
      #pragma unroll 4
      for (int c4=0;c4<32;c4++){
        float4 dv = *(const float4*)&DNP[row*132 + c4*4];
        const float* wr = am + (3 + c4*4)*128 + f0;
        #pragma unroll
        for (int j=0;j<8;j++) e[j] = fmaf(dv.x, wr[j],     e[j]);
        #pragma unroll
        for (int j=0;j<8;j++) e[j] = fmaf(dv.y, wr[128+j], e[j]);
        #pragma unroll
        for (int j=0;j<8;j++) e[j] = fmaf(dv.z, wr[256+j], e[j]);
        #pragma unroll
        for (int j=0;j<8;j++) e[j] = fmaf(dv.w, wr[384+j], e[j]);
      }
      #pragma unroll
      for (int j=0;j<8;j++){
        float ej = e[j]; ej = (ej >= 0.0f) ? ej : 0.2f*ej;
        float mx = ej;
        mx = fmaxf(mx, __shfl_xor(mx,1));
        mx = fmaxf(mx, __shfl_xor(mx,2));
        mx = fmaxf(mx, __shfl_xor(mx,4));
        mx = fmaxf(mx, __shfl_xor(mx,8));
        mx = fmaxf(mx, __shfl_xor(mx,16));
        float pp = __expf(ej - mx);
        float sm = pp;
        sm += __shfl_xor(sm,1); sm += __shfl_xor(sm,2); sm += __shfl_xor(sm,4);
        sm += __shfl_xor(sm,8); sm += __shfl_xor(sm,16);
        float po = (pp / sm) * np[p*8+j];
        po += __shfl_xor(po,1); po += __shfl_xor(po,2); po += __shfl_xor(po,4);
        po += __shfl_xor(po,8); po += __shfl_xor(po,16);
        if (k == 0) out1[ob + (size_t)(f0+j)*SS] = po;
      }
    }
  }
}

extern "C" void kernel_launch(void* const* d_in, const int* in_sizes, int n_in,
                              void* d_out, int out_size, void* d_ws, size_t ws_size,
                              hipStream_t stream){
  (void)in_sizes; (void)n_in; (void)out_size; (void)ws_size;
  const float* xyz    = (const float*)d_in[0];
  const float* points = (const float*)d_in[1];
  const float* am     = (const float*)d_in[20];
  float* ws  = (float*)d_ws;
  int*   fpsidx = (int*)d_ws + FPSIDX_OFF;
  int*   gidx   = (int*)d_ws + GIDX_OFF;
  float* nrm    = ws + NORM_OFF;
  float* fpin   = ws + FPIN_OFF;
  float* wf     = ws + WF_OFF;
  float* out0   = (float*)d_out;
  float* out1   = (float*)d_out + BB*3*SS;

  k_fold<<<1,128,0,stream>>>(
      (const float*)d_in[2],(const float*)d_in[3],(const float*)d_in[4],(const float*)d_in[5],(const float*)d_in[6],(const float*)d_in[7],
      (const float*)d_in[8],(const float*)d_in[9],(const float*)d_in[10],(const float*)d_in[11],(const float*)d_in[12],(const float*)d_in[13],
      (const float*)d_in[14],(const float*)d_in[15],(const float*)d_in[16],(const float*)d_in[17],(const float*)d_in[18],(const float*)d_in[19],
      wf);
  k_norm<<<BB*NN/256,256,0,stream>>>(xyz, nrm);
  k_fps<<<BB,256,0,stream>>>(xyz, fpsidx);
  k_ball<<<BB*SS/4,256,0,stream>>>(xyz, points, nrm, fpsidx, gidx, fpin, out0);
  k_fused<<<BB*SS/2,256,0,stream>>>(xyz, points, am, wf, gidx, fpin, out1);
}